// Round 2
// baseline (2839.989 us; speedup 1.0000x reference)
//
#include <hip/hip_runtime.h>
#include <math.h>

#define D 512
#define P 8
#define NL 4
#define BB 2
#define LL 2048
#define VV 32000
#define MTOK (BB*LL)   // 4096
#define CH 128
#define NCH (LL/CH)    // 16

__device__ __forceinline__ float softplusf(float x){
    if (x > 20.f) return x;
    return log1pf(expf(x));
}

// ---------------- embedding gather: h[t,:] = embed[tokens[t],:] ----------------
__global__ void gather_kernel(const int* __restrict__ tokens,
                              const float* __restrict__ embed,
                              float* __restrict__ h){
    int t = blockIdx.x;
    int tok = tokens[t];
    const float4* src = (const float4*)(embed + (size_t)tok * D);
    float4* dst = (float4*)(h + (size_t)t * D);
    dst[threadIdx.x] = src[threadIdx.x];
}

// ---------------- per-token LayerNorm (block = 128 threads, D=512) -------------
__global__ void ln_kernel(const float* __restrict__ x,
                          const float* __restrict__ g,
                          const float* __restrict__ b,
                          float* __restrict__ y){
    int t = blockIdx.x;
    int tid = threadIdx.x;
    const float4* xr = (const float4*)(x + (size_t)t * D);
    float4 v = xr[tid];
    float s = v.x + v.y + v.z + v.w;
    float q = v.x*v.x + v.y*v.y + v.z*v.z + v.w*v.w;
    #pragma unroll
    for (int off = 32; off; off >>= 1){
        s += __shfl_down(s, off);
        q += __shfl_down(q, off);
    }
    __shared__ float red[4];
    int wid = tid >> 6, lane = tid & 63;
    if (lane == 0){ red[wid] = s; red[2 + wid] = q; }
    __syncthreads();
    float mean = (red[0] + red[1]) * (1.f / D);
    float var  = (red[2] + red[3]) * (1.f / D) - mean * mean;
    float rstd = rsqrtf(var + 1e-5f);
    float4 gg = ((const float4*)g)[tid];
    float4 bb = ((const float4*)b)[tid];
    float4 o;
    o.x = (v.x - mean) * rstd * gg.x + bb.x;
    o.y = (v.y - mean) * rstd * gg.y + bb.y;
    o.z = (v.z - mean) * rstd * gg.z + bb.z;
    o.w = (v.w - mean) * rstd * gg.w + bb.w;
    ((float4*)(y + (size_t)t * D))[tid] = o;
}

// --------- phase/amp projections + per-token coefficient c (1 wave/token) ------
__global__ void proj_kernel(const float* __restrict__ hn,
                            const float* __restrict__ pW, const float* __restrict__ pb,
                            const float* __restrict__ aW, const float* __restrict__ ab,
                            float* __restrict__ cbuf){
    int wid = threadIdx.x >> 6;
    int lane = threadIdx.x & 63;
    int t = blockIdx.x * 4 + wid;
    const float* x = hn + (size_t)t * D;
    float ph[P] = {0.f,0.f,0.f,0.f,0.f,0.f,0.f,0.f};
    float am[P] = {0.f,0.f,0.f,0.f,0.f,0.f,0.f,0.f};
    int d0 = lane * 8;
    #pragma unroll
    for (int j = 0; j < 8; j++){
        float xv = x[d0 + j];
        const float* pr = pW + (size_t)(d0 + j) * P;
        const float* ar = aW + (size_t)(d0 + j) * P;
        #pragma unroll
        for (int p = 0; p < P; p++){ ph[p] += xv * pr[p]; am[p] += xv * ar[p]; }
    }
    #pragma unroll
    for (int off = 32; off; off >>= 1){
        #pragma unroll
        for (int p = 0; p < P; p++){
            ph[p] += __shfl_down(ph[p], off);
            am[p] += __shfl_down(am[p], off);
        }
    }
    if (lane == 0){
        float c = 0.f;
        #pragma unroll
        for (int p = 0; p < P; p++){
            float phase = tanhf(ph[p] + pb[p]) * 3.14159265358979323846f;
            float amp = softplusf(am[p] + ab[p]) + 0.1f;
            c += amp * (cosf(phase) + sinf(phase));
        }
        cbuf[t] = c;
    }
}

// ---------------- generic fp32 tiled GEMM: C = epi(A@B + bias) -----------------
// A: MxK row-major, B: KxN row-major. epilogue: v=(acc+bias[n]); v*=rowscale[m];
// v+=R1; v+=R2; C=v.   BM=BN=64, BK=16, 256 thr, 4x4 micro-tile.
__global__ __launch_bounds__(256) void gemm_kernel(
    const float* __restrict__ A, const float* __restrict__ B,
    const float* __restrict__ bias, const float* __restrict__ rowscale,
    const float* __restrict__ R1, const float* __restrict__ R2,
    float* __restrict__ C, int M, int N, int K)
{
    __shared__ float As[16][64];
    __shared__ float Bs[16][64];
    int bn = blockIdx.x * 64, bm = blockIdx.y * 64;
    int tid = threadIdx.x;
    int tx = tid & 15, ty = tid >> 4;
    float acc[4][4] = {};
    int arow = tid >> 2, acol = (tid & 3) * 4;
    int brow = tid >> 4, bcol = (tid & 15) * 4;
    for (int k0 = 0; k0 < K; k0 += 16){
        float4 av = *(const float4*)(A + (size_t)(bm + arow) * K + k0 + acol);
        As[acol + 0][arow] = av.x; As[acol + 1][arow] = av.y;
        As[acol + 2][arow] = av.z; As[acol + 3][arow] = av.w;
        float4 bv = *(const float4*)(B + (size_t)(k0 + brow) * N + bn + bcol);
        *(float4*)(&Bs[brow][bcol]) = bv;
        __syncthreads();
        #pragma unroll
        for (int k = 0; k < 16; k++){
            float ar[4], br[4];
            #pragma unroll
            for (int i = 0; i < 4; i++) ar[i] = As[k][ty * 4 + i];
            #pragma unroll
            for (int j = 0; j < 4; j++) br[j] = Bs[k][tx * 4 + j];
            #pragma unroll
            for (int i = 0; i < 4; i++)
                #pragma unroll
                for (int j = 0; j < 4; j++)
                    acc[i][j] += ar[i] * br[j];
        }
        __syncthreads();
    }
    float4 bi = *(const float4*)(bias + bn + tx * 4);
    #pragma unroll
    for (int i = 0; i < 4; i++){
        int m = bm + ty * 4 + i;
        float rs = rowscale ? rowscale[m] : 1.f;
        size_t idx = (size_t)m * N + bn + tx * 4;
        float4 v;
        v.x = (acc[i][0] + bi.x) * rs;
        v.y = (acc[i][1] + bi.y) * rs;
        v.z = (acc[i][2] + bi.z) * rs;
        v.w = (acc[i][3] + bi.w) * rs;
        if (R1){
            float4 r = *(const float4*)(R1 + idx);
            v.x += r.x; v.y += r.y; v.z += r.z; v.w += r.w;
        }
        if (R2){
            float4 r = *(const float4*)(R2 + idx);
            v.x += r.x; v.y += r.y; v.z += r.z; v.w += r.w;
        }
        *(float4*)(C + idx) = v;
    }
}

// ---------------- 3-phase chunked prefix sum over L, coalesced in d ------------
__global__ void scan1_kernel(const float* __restrict__ s, float* __restrict__ partial){
    int id = blockIdx.x;           // 64 blocks: b(2) x ch(16) x dblk(2)
    int b = id >> 5;
    int rem = id & 31;
    int ch = rem >> 1;
    int d = (rem & 1) * 256 + threadIdx.x;
    const float* base = s + ((size_t)b * LL + (size_t)ch * CH) * D + d;
    float sum = 0.f;
    for (int l = 0; l < CH; l++) sum += base[(size_t)l * D];
    partial[((size_t)b * D + d) * NCH + ch] = sum;
}

__global__ void scan2_kernel(float* __restrict__ partial){
    int t = blockIdx.x * 256 + threadIdx.x;   // 1024 = B*D channels
    float run = 0.f;
    float* p = partial + (size_t)t * NCH;
    for (int ch = 0; ch < NCH; ch++){ float v = p[ch]; p[ch] = run; run += v; }
}

__global__ void scan3_kernel(const float* __restrict__ s, const float* __restrict__ partial,
                             float* __restrict__ ret){
    int id = blockIdx.x;
    int b = id >> 5;
    int rem = id & 31;
    int ch = rem >> 1;
    int d = (rem & 1) * 256 + threadIdx.x;
    float run = partial[((size_t)b * D + d) * NCH + ch];
    const float invs = 0.022097086912079608f;  // 1/sqrt(2048)
    const float* base = s + ((size_t)b * LL + (size_t)ch * CH) * D + d;
    float* obase = ret + ((size_t)b * LL + (size_t)ch * CH) * D + d;
    for (int l = 0; l < CH; l++){
        run += base[(size_t)l * D];
        obase[(size_t)l * D] = run * invs;
    }
}

extern "C" void kernel_launch(void* const* d_in, const int* in_sizes, int n_in,
                              void* d_out, int out_size, void* d_ws, size_t ws_size,
                              hipStream_t stream) {
    const int*   tokens        = (const int*)  d_in[0];
    const float* embed         = (const float*)d_in[1];
    const float* ln_scale      = (const float*)d_in[2];
    const float* ln_bias       = (const float*)d_in[3];
    const float* phase_W       = (const float*)d_in[4];
    const float* phase_b       = (const float*)d_in[5];
    const float* amp_W         = (const float*)d_in[6];
    const float* amp_b         = (const float*)d_in[7];
    const float* value_W       = (const float*)d_in[8];
    const float* value_b       = (const float*)d_in[9];
    const float* out_ln_scale  = (const float*)d_in[10];
    const float* out_ln_bias   = (const float*)d_in[11];
    const float* out_W         = (const float*)d_in[12];
    const float* out_b         = (const float*)d_in[13];
    const float* normout_scale = (const float*)d_in[14];
    const float* normout_bias  = (const float*)d_in[15];
    const float* head_W        = (const float*)d_in[16];
    const float* head_b        = (const float*)d_in[17];
    float* out = (float*)d_out;

    float* ws   = (float*)d_ws;
    float* h    = ws;                    // MTOK*D
    float* hn   = h    + (size_t)MTOK*D; // MTOK*D
    float* sbuf = hn   + (size_t)MTOK*D; // MTOK*D
    float* rbuf = sbuf + (size_t)MTOK*D; // MTOK*D
    float* cbuf = rbuf + (size_t)MTOK*D; // MTOK
    float* part = cbuf + MTOK;           // B*D*NCH

    gather_kernel<<<MTOK, 128, 0, stream>>>(tokens, embed, h);

    for (int i = 0; i < NL; i++){
        ln_kernel<<<MTOK, 128, 0, stream>>>(h, ln_scale + i*D, ln_bias + i*D, hn);
        proj_kernel<<<MTOK/4, 256, 0, stream>>>(hn,
            phase_W + (size_t)i*D*P, phase_b + i*P,
            amp_W   + (size_t)i*D*P, amp_b   + i*P, cbuf);
        dim3 g1(D/64, MTOK/64);
        // sbuf = (hn @ vW + vb) * c
        gemm_kernel<<<g1, 256, 0, stream>>>(hn, value_W + (size_t)i*D*D, value_b + i*D,
                                            cbuf, nullptr, nullptr, sbuf, MTOK, D, D);
        scan1_kernel<<<64, 256, 0, stream>>>(sbuf, part);
        scan2_kernel<<<4, 256, 0, stream>>>(part);
        scan3_kernel<<<64, 256, 0, stream>>>(sbuf, part, rbuf);
        // rbuf = LN(rbuf) with out_ln params (in-place safe: per-thread read-before-write)
        ln_kernel<<<MTOK, 128, 0, stream>>>(rbuf, out_ln_scale + i*D, out_ln_bias + i*D, rbuf);
        // h = h + hn + (rbuf @ oW + ob)
        gemm_kernel<<<g1, 256, 0, stream>>>(rbuf, out_W + (size_t)i*D*D, out_b + i*D,
                                            nullptr, h, hn, h, MTOK, D, D);
    }

    ln_kernel<<<MTOK, 128, 0, stream>>>(h, normout_scale, normout_bias, hn);
    dim3 gh(VV/64, MTOK/64);
    gemm_kernel<<<gh, 256, 0, stream>>>(hn, head_W, head_b,
                                        nullptr, nullptr, nullptr, out, MTOK, VV, D);
}